// Round 4
// baseline (102.805 us; speedup 1.0000x reference)
//
#include <hip/hip_runtime.h>

// RelativePositionEncoding (AF3-style), B=1, N=1024, C_PAIR=128
// W rows: Wp = 0..65, Wt = 66..131, w_ent = 132, Wc = 133..138 (D_IN = 139)

#define C_PAIR 128
#define N_COMBO 152
#define NTOK 1024

typedef float f4 __attribute__((ext_vector_type(4)));

// combo id encoding (covers every reachable (idx_pos, idx_tok, idx_chain, se)):
//   same-chain & same-residue : cid = clamp(ti-tj+32,0,64) + se*65            -> [0,129]
//   same-chain & !same-residue: cid = 130 + se                                -> [130,131]
//   diff-chain                : cid = 132 + clamp(si-sj+2,0,4) + sr*5 + se*10 -> [132,151]
__device__ __forceinline__ int combo_id(int ri, int ai, int ei, int ti, int si,
                                        int rj, int aj, int ej, int tj, int sj) {
    const bool sr = (ri == rj);
    const bool sc = (ai == aj);
    const bool se = (ei == ej);
    int cid;
    if (sc) {
        if (sr) {
            int dt = ti - tj + 32;
            dt = dt < 0 ? 0 : (dt > 64 ? 64 : dt);
            cid = dt + (se ? 65 : 0);
        } else {
            cid = 130 + (se ? 1 : 0);
        }
    } else {
        int dc = si - sj + 2;
        dc = dc < 0 ? 0 : (dc > 4 ? 4 : dc);
        cid = 132 + dc + (sr ? 5 : 0) + (se ? 10 : 0);
    }
    return cid;
}

__device__ __forceinline__ void decode_cid(int cid, int& idx_pos, int& idx_tok,
                                           int& idx_chain, int& se) {
    if (cid < 130) {
        se = cid >= 65 ? 1 : 0;
        idx_pos = 32; idx_tok = cid - se * 65; idx_chain = 5;
    } else if (cid < 132) {
        se = cid - 130;
        idx_pos = 65; idx_tok = 65; idx_chain = 5;
    } else {
        int r = cid - 132;
        se = r >= 10 ? 1 : 0; r -= se * 10;
        const int sr = r >= 5 ? 1 : 0; r -= sr * 5;
        idx_pos = sr ? 32 : 65; idx_tok = 65; idx_chain = r;
    }
}

// One block per row i. Prologue builds s_cid[1024] and the combined table
// s_T[152][32] (f4) in LDS; store loop is LDS-fed only: per pair
// 1 ds_read_u16 + 1 ds_read_b128 + 1 global_store_dwordx4.
__global__ __launch_bounds__(256) void rpe_fused(
    const int* __restrict__ res, const int* __restrict__ tok,
    const int* __restrict__ asym, const int* __restrict__ ent,
    const int* __restrict__ sym, const float* __restrict__ W,
    float* __restrict__ out)
{
    __shared__ f4 s_T[N_COMBO * 32];            // 77824 B
    __shared__ unsigned short s_cid[NTOK];      // 2048 B

    const int i = blockIdx.x;
    const int t = threadIdx.x;

    // i-scalars (wave-uniform -> scalar loads)
    const int ri = res[i], ai = asym[i], ei = ent[i], ti = tok[i], si = sym[i];

    // cid for all 1024 j (coalesced scalar loads, once per pair)
    #pragma unroll
    for (int k = 0; k < NTOK / 256; ++k) {
        const int j = t + k * 256;
        s_cid[j] = (unsigned short)combo_id(ri, ai, ei, ti, si,
                       res[j], asym[j], ent[j], tok[j], sym[j]);
    }

    // combined table directly in LDS: 152*32 = 4864 f4, 19 per thread.
    // Same fp32 add order as reference: ((p + t) + fe*e) + ch  -> bit-identical.
    #pragma unroll
    for (int k = 0; k < 19; ++k) {
        const int idx = t + k * 256;            // f4 index into T
        const int cid = idx >> 5;               // 32 f4 per row
        const int ch  = idx & 31;
        int ip, it, ic, se;
        decode_cid(cid, ip, it, ic, se);
        const f4 p  = ((const f4*)(W + (size_t)ip * C_PAIR))[ch];
        const f4 tk = ((const f4*)(W + (size_t)(66 + it) * C_PAIR))[ch];
        const f4 e  = ((const f4*)(W + (size_t)132 * C_PAIR))[ch];
        const f4 c  = ((const f4*)(W + (size_t)(133 + ic) * C_PAIR))[ch];
        const float fe = se ? 1.0f : 0.0f;
        f4 r;
        r.x = ((p.x + tk.x) + fe * e.x) + c.x;
        r.y = ((p.y + tk.y) + fe * e.y) + c.y;
        r.z = ((p.z + tk.z) + fe * e.z) + c.z;
        r.w = ((p.w + tk.w) + fe * e.w) + c.w;
        s_T[idx] = r;
    }
    __syncthreads();

    // store loop: 8 pairs per iteration (sub = pair-in-group, ch = f4 chunk)
    const int sub = t >> 5;                     // 0..7
    const int ch  = t & 31;                     // 0..31
    f4* o = (f4*)out + ((size_t)i * NTOK + sub) * 32 + ch;
    #pragma unroll 8
    for (int jb = 0; jb < NTOK / 8; ++jb) {
        const int j = jb * 8 + sub;
        const int cid = s_cid[j];
        o[(size_t)jb * 256] = s_T[cid * 32 + ch];
    }
}

// Fallback for unexpected N (direct 4-load version, round-1 kernel)
__global__ __launch_bounds__(256) void rpe_direct(
    const int* __restrict__ res, const int* __restrict__ tok,
    const int* __restrict__ asym, const int* __restrict__ ent,
    const int* __restrict__ sym, const float* __restrict__ W,
    float* __restrict__ out, int N, int blocks_per_row)
{
    const int bid = blockIdx.x;
    const int i  = bid / blocks_per_row;
    const int jb = bid - i * blocks_per_row;
    const int t  = threadIdx.x;
    const int j  = jb * 8 + (t >> 5);
    const int c4 = t & 31;

    const int ri = res[i],  rj = res[j];
    const int ai = asym[i], aj = asym[j];
    const int ei = ent[i],  ej = ent[j];
    const int ti = tok[i],  tj = tok[j];
    const int si = sym[i],  sj = sym[j];

    const bool sr = (ri == rj);
    const bool sc = (ai == aj);
    const bool se = (ei == ej);

    const int idx_pos = sr ? 32 : 65;
    int dt = ti - tj + 32; dt = dt < 0 ? 0 : (dt > 64 ? 64 : dt);
    const int idx_tok = (sr && sc) ? dt : 65;
    int dc = si - sj + 2; dc = dc < 0 ? 0 : (dc > 4 ? 4 : dc);
    const int idx_chain = (!sc) ? dc : 5;

    const f4 p  = ((const f4*)(W + (size_t)idx_pos * C_PAIR))[c4];
    const f4 tk = ((const f4*)(W + (size_t)(66 + idx_tok) * C_PAIR))[c4];
    const f4 e  = ((const f4*)(W + (size_t)132 * C_PAIR))[c4];
    const f4 c  = ((const f4*)(W + (size_t)(133 + idx_chain) * C_PAIR))[c4];
    const float fe = se ? 1.0f : 0.0f;

    f4 r;
    r.x = ((p.x + tk.x) + fe * e.x) + c.x;
    r.y = ((p.y + tk.y) + fe * e.y) + c.y;
    r.z = ((p.z + tk.z) + fe * e.z) + c.z;
    r.w = ((p.w + tk.w) + fe * e.w) + c.w;

    ((f4*)(out + ((size_t)i * N + j) * C_PAIR))[c4] = r;
}

extern "C" void kernel_launch(void* const* d_in, const int* in_sizes, int n_in,
                              void* d_out, int out_size, void* d_ws, size_t ws_size,
                              hipStream_t stream) {
    const int* res  = (const int*)d_in[0];
    const int* tok  = (const int*)d_in[1];
    const int* asym = (const int*)d_in[2];
    const int* ent  = (const int*)d_in[3];
    const int* sym  = (const int*)d_in[4];
    const float* W  = (const float*)d_in[5];
    float* out = (float*)d_out;

    const int N = in_sizes[0];

    if (N == NTOK) {
        rpe_fused<<<NTOK, 256, 0, stream>>>(res, tok, asym, ent, sym, W, out);
    } else {
        const int blocks_per_row = N / 8;
        rpe_direct<<<N * blocks_per_row, 256, 0, stream>>>(res, tok, asym, ent, sym,
                                                           W, out, N, blocks_per_row);
    }
}